// Round 2
// baseline (5519.357 us; speedup 1.0000x reference)
//
#include <hip/hip_runtime.h>
#include <math.h>

#define BTN (8*512*128)   // 524288 rows (b,t,n)
#define T_  512
#define N_  128
#define H_  32

__device__ __forceinline__ float sigm(float x)  { return 1.0f / (1.0f + __expf(-x)); }
__device__ __forceinline__ float tanhf_(float x){ return 1.0f - 2.0f / (1.0f + __expf(2.0f * x)); }

// ---------------------------------------------------------------------------
// Kernel 1: xres = X @ in_w[:,64:96] + in_b[64:96]
// ---------------------------------------------------------------------------
__global__ __launch_bounds__(256) void k_in(const float* __restrict__ X,
                                            const float* __restrict__ w,
                                            const float* __restrict__ b,
                                            float* __restrict__ xres)
{
    int p = blockIdx.x * 256 + threadIdx.x;
    float x[16];
    const float4* xr = (const float4*)(X + (size_t)p * 16);
#pragma unroll
    for (int k = 0; k < 4; ++k) {
        float4 v = xr[k];
        x[4*k+0] = v.x; x[4*k+1] = v.y; x[4*k+2] = v.z; x[4*k+3] = v.w;
    }
    float acc[32];
#pragma unroll
    for (int j = 0; j < 32; ++j) acc[j] = b[64 + j];
#pragma unroll
    for (int k = 0; k < 16; ++k) {
        float xv = x[k];
#pragma unroll
        for (int j = 0; j < 32; ++j)
            acc[j] = fmaf(xv, w[k*96 + 64 + j], acc[j]);
    }
    float4* o = (float4*)(xres + (size_t)p * 32);
#pragma unroll
    for (int q = 0; q < 8; ++q)
        o[q] = make_float4(acc[4*q], acc[4*q+1], acc[4*q+2], acc[4*q+3]);
}

// ---------------------------------------------------------------------------
// Kernel 2 (per layer): one block per (b,t).
//   - recompute input projections xa/xb for rows (s=b*128+i, t) and (s, t-d)
//   - gated causal conv in registers (natively in transposed coords)
//   - Ax = A @ xres_tile (LDS) ; gcn = Ax@gw+gb ; h = tcn + gcn
//   - xres += h@rw+rb ; skip (+)= h@sw+sb
// ---------------------------------------------------------------------------
__global__ __launch_bounds__(256) void k_layer(const float* __restrict__ X,
                                               const float* __restrict__ A,
                                               const float* __restrict__ in_w,
                                               const float* __restrict__ in_b,
                                               const float* __restrict__ wt,
                                               const float* __restrict__ bt,
                                               const float* __restrict__ wsg,
                                               const float* __restrict__ bsg,
                                               const float* __restrict__ gw,
                                               const float* __restrict__ gb,
                                               const float* __restrict__ rw,
                                               const float* __restrict__ rb,
                                               const float* __restrict__ sw,
                                               const float* __restrict__ sb,
                                               float* __restrict__ xres,
                                               float* __restrict__ skip,
                                               int d, int first)
{
    __shared__ float xs[128 * 32];    // xres tile (broadcast reads only)
    __shared__ float t2s[128 * 36];   // Ax then h; stride 36

    int btid = blockIdx.x;            // b*512 + t
    int b = btid >> 9, t = btid & (T_ - 1);
    int tid = threadIdx.x;
    int i = tid & 127;                // node
    int fh = tid >> 7;                // wave-uniform half: out channels fh*16..fh*16+15
    int fh16 = fh * 16;
    size_t rowbase = (size_t)btid * 128 * 32;

    // phase 0: stage xres tile (16 KB) coalesced; consumed after first sync
    {
        const float4* src = (const float4*)(xres + rowbase);
        float4* dst = (float4*)xs;
#pragma unroll
        for (int k = 0; k < 4; ++k) dst[tid + 256*k] = src[tid + 256*k];
    }

    // phase 1: conv for node s = b*128+i at time t (block-uniform validity t>=d)
    bool pv = (t >= d);
    size_t q0 = ((size_t)(b*128 + i) * 512 + t);   // row index into X
    float Xc[16], Xp[16];
    {
        const float4* c4 = (const float4*)(X + q0 * 16);
#pragma unroll
        for (int k = 0; k < 4; ++k) {
            float4 v = c4[k];
            Xc[4*k+0] = v.x; Xc[4*k+1] = v.y; Xc[4*k+2] = v.z; Xc[4*k+3] = v.w;
        }
        if (pv) {
            const float4* p4 = (const float4*)(X + (q0 - (size_t)d) * 16);
#pragma unroll
            for (int k = 0; k < 4; ++k) {
                float4 v = p4[k];
                Xp[4*k+0] = v.x; Xp[4*k+1] = v.y; Xp[4*k+2] = v.z; Xp[4*k+3] = v.w;
            }
        } else {
#pragma unroll
            for (int k = 0; k < 16; ++k) Xp[k] = 0.f;
        }
    }

    float tc[16];   // gated conv output for channels [fh16, fh16+16)
    {
        float cur[32], prv[32];
        // --- branch A (proj channels [0,32)) -> tanh conv ---
#pragma unroll
        for (int ci = 0; ci < 32; ++ci) {
            float a = in_b[ci], p2 = in_b[ci];
#pragma unroll
            for (int k = 0; k < 16; ++k) {
                a  = fmaf(Xc[k], in_w[k*96 + ci], a);
                p2 = fmaf(Xp[k], in_w[k*96 + ci], p2);
            }
            cur[ci] = a;
            prv[ci] = pv ? p2 : 0.f;
        }
        float g[16];
#pragma unroll
        for (int co = 0; co < 16; ++co) g[co] = bt[fh16 + co];
#pragma unroll
        for (int ci = 0; ci < 32; ++ci) {
            float a0 = prv[ci], a1 = cur[ci];
#pragma unroll
            for (int co = 0; co < 16; ++co)
                g[co] = fmaf(a0, wt[ci*32 + fh16 + co],
                        fmaf(a1, wt[1024 + ci*32 + fh16 + co], g[co]));
        }
        // --- branch B (proj channels [32,64)) -> sigmoid conv ---
#pragma unroll
        for (int ci = 0; ci < 32; ++ci) {
            float a = in_b[32 + ci], p2 = in_b[32 + ci];
#pragma unroll
            for (int k = 0; k < 16; ++k) {
                a  = fmaf(Xc[k], in_w[k*96 + 32 + ci], a);
                p2 = fmaf(Xp[k], in_w[k*96 + 32 + ci], p2);
            }
            cur[ci] = a;
            prv[ci] = pv ? p2 : 0.f;
        }
        float ac[16];
#pragma unroll
        for (int co = 0; co < 16; ++co) ac[co] = bsg[fh16 + co];
#pragma unroll
        for (int ci = 0; ci < 32; ++ci) {
            float a0 = prv[ci], a1 = cur[ci];
#pragma unroll
            for (int co = 0; co < 16; ++co)
                ac[co] = fmaf(a0, wsg[ci*32 + fh16 + co],
                         fmaf(a1, wsg[1024 + ci*32 + fh16 + co], ac[co]));
        }
#pragma unroll
        for (int co = 0; co < 16; ++co)
            tc[co] = tanhf_(g[co]) * sigm(ac[co]);
    }

    __syncthreads();   // xs tile ready

    // phase 2: Ax[i, fh16..fh16+15] = sum_j A[i,j] * xs[j, :]
    float acc[16];
#pragma unroll
    for (int q = 0; q < 16; ++q) acc[q] = 0.f;
    const float* Arow = A + i * 128;
    for (int j = 0; j < 128; ++j) {
        float a = Arow[j];
        const float4* xr = (const float4*)(xs + j*32 + fh16);  // wave-uniform -> broadcast
#pragma unroll
        for (int q = 0; q < 4; ++q) {
            float4 v = xr[q];
            acc[4*q+0] = fmaf(a, v.x, acc[4*q+0]);
            acc[4*q+1] = fmaf(a, v.y, acc[4*q+1]);
            acc[4*q+2] = fmaf(a, v.z, acc[4*q+2]);
            acc[4*q+3] = fmaf(a, v.w, acc[4*q+3]);
        }
    }
    float4* t4 = (float4*)(t2s + i*36 + fh16);
#pragma unroll
    for (int q = 0; q < 4; ++q)
        t4[q] = make_float4(acc[4*q], acc[4*q+1], acc[4*q+2], acc[4*q+3]);
    __syncthreads();

    // phase 3: gcn = Ax_row @ gw + gb ; h = tcn + gcn
    float axr[32];
    {
        const float4* rr = (const float4*)(t2s + i*36);
#pragma unroll
        for (int q = 0; q < 8; ++q) {
            float4 v = rr[q];
            axr[4*q+0] = v.x; axr[4*q+1] = v.y; axr[4*q+2] = v.z; axr[4*q+3] = v.w;
        }
    }
    float h[16];
#pragma unroll
    for (int q = 0; q < 16; ++q) h[q] = gb[fh16 + q];
#pragma unroll
    for (int f = 0; f < 32; ++f) {
        float av = axr[f];
#pragma unroll
        for (int q = 0; q < 16; ++q)
            h[q] = fmaf(av, gw[f*32 + fh16 + q], h[q]);
    }
#pragma unroll
    for (int q = 0; q < 16; ++q) h[q] += tc[q];

    __syncthreads();   // everyone done reading Ax
#pragma unroll
    for (int q = 0; q < 4; ++q)
        t4[q] = make_float4(h[4*q], h[4*q+1], h[4*q+2], h[4*q+3]);
    __syncthreads();

    // phase 4: res & skip mixes from full h row
    float hr[32];
    {
        const float4* rr = (const float4*)(t2s + i*36);
#pragma unroll
        for (int q = 0; q < 8; ++q) {
            float4 v = rr[q];
            hr[4*q+0] = v.x; hr[4*q+1] = v.y; hr[4*q+2] = v.z; hr[4*q+3] = v.w;
        }
    }
    float r[16], s[16];
#pragma unroll
    for (int q = 0; q < 16; ++q) { r[q] = rb[fh16 + q]; s[q] = sb[fh16 + q]; }
#pragma unroll
    for (int f = 0; f < 32; ++f) {
        float hv = hr[f];
#pragma unroll
        for (int q = 0; q < 16; ++q) {
            r[q] = fmaf(hv, rw[f*32 + fh16 + q], r[q]);
            s[q] = fmaf(hv, sw[f*32 + fh16 + q], s[q]);
        }
    }
    {
        float4* xg = (float4*)(xres + rowbase + i*32 + fh16);
        float4* sg = (float4*)(skip + rowbase + i*32 + fh16);
#pragma unroll
        for (int q = 0; q < 4; ++q) {
            float4 v = xg[q];
            xg[q] = make_float4(v.x + r[4*q+0], v.y + r[4*q+1], v.z + r[4*q+2], v.w + r[4*q+3]);
            if (first) {
                sg[q] = make_float4(s[4*q+0], s[4*q+1], s[4*q+2], s[4*q+3]);
            } else {
                float4 u = sg[q];
                sg[q] = make_float4(u.x + s[4*q+0], u.y + s[4*q+1], u.z + s[4*q+2], u.w + s[4*q+3]);
            }
        }
    }
}

// ---------------------------------------------------------------------------
// Kernel 3: output head.  out = relu(relu(skip) @ w1 + b1) @ w2 + b2
// ---------------------------------------------------------------------------
__global__ __launch_bounds__(256) void k_out(const float* __restrict__ skip,
                                             const float* __restrict__ w1,
                                             const float* __restrict__ b1,
                                             const float* __restrict__ w2,
                                             const float* __restrict__ b2,
                                             float* __restrict__ out)
{
    int p = blockIdx.x * 256 + threadIdx.x;
    float sv[32];
    {
        const float4* sr = (const float4*)(skip + (size_t)p * 32);
#pragma unroll
        for (int q = 0; q < 8; ++q) {
            float4 v = sr[q];
            sv[4*q+0] = fmaxf(v.x, 0.f); sv[4*q+1] = fmaxf(v.y, 0.f);
            sv[4*q+2] = fmaxf(v.z, 0.f); sv[4*q+3] = fmaxf(v.w, 0.f);
        }
    }
    float h[32];
#pragma unroll
    for (int j = 0; j < 32; ++j) h[j] = b1[j];
#pragma unroll
    for (int f = 0; f < 32; ++f) {
        float x = sv[f];
#pragma unroll
        for (int j = 0; j < 32; ++j) h[j] = fmaf(x, w1[f*32 + j], h[j]);
    }
#pragma unroll
    for (int j = 0; j < 32; ++j) h[j] = fmaxf(h[j], 0.f);

    float o[16];
#pragma unroll
    for (int j = 0; j < 16; ++j) o[j] = b2[j];
#pragma unroll
    for (int f = 0; f < 32; ++f) {
        float x = h[f];
#pragma unroll
        for (int j = 0; j < 16; ++j) o[j] = fmaf(x, w2[f*16 + j], o[j]);
    }
    float4* og = (float4*)(out + (size_t)p * 16);
#pragma unroll
    for (int q = 0; q < 4; ++q)
        og[q] = make_float4(o[4*q], o[4*q+1], o[4*q+2], o[4*q+3]);
}

// ---------------------------------------------------------------------------
extern "C" void kernel_launch(void* const* d_in, const int* in_sizes, int n_in,
                              void* d_out, int out_size, void* d_ws, size_t ws_size,
                              hipStream_t stream)
{
    const float* X      = (const float*)d_in[0];
    const float* A      = (const float*)d_in[1];
    const float* in_w   = (const float*)d_in[2];
    const float* in_b   = (const float*)d_in[3];
    const float* ct_w   = (const float*)d_in[4];
    const float* ct_b   = (const float*)d_in[5];
    const float* cs_w   = (const float*)d_in[6];
    const float* cs_b   = (const float*)d_in[7];
    const float* gcn_w  = (const float*)d_in[8];
    const float* gcn_b  = (const float*)d_in[9];
    const float* res_w  = (const float*)d_in[10];
    const float* res_b  = (const float*)d_in[11];
    const float* skip_w = (const float*)d_in[12];
    const float* skip_b = (const float*)d_in[13];
    const float* out1_w = (const float*)d_in[14];
    const float* out1_b = (const float*)d_in[15];
    const float* out2_w = (const float*)d_in[16];
    const float* out2_b = (const float*)d_in[17];

    float* ws = (float*)d_ws;
    const size_t SZ = (size_t)BTN * 32;   // 16.78M floats per activation buffer
    float* xres = ws;           // 67.1 MB
    float* skip = ws + SZ;      // 67.1 MB   (total d_ws use: 134.2 MB)

    k_in<<<BTN/256, 256, 0, stream>>>(X, in_w, in_b, xres);

    for (int l = 0; l < 4; ++l) {
        int d = 1 << l;
        k_layer<<<8*T_, 256, 0, stream>>>(X, A, in_w, in_b,
                                          ct_w + l*2048, ct_b + l*32,
                                          cs_w + l*2048, cs_b + l*32,
                                          gcn_w + l*1024, gcn_b + l*32,
                                          res_w + l*1024, res_b + l*32,
                                          skip_w + l*1024, skip_b + l*32,
                                          xres, skip, d, (l == 0) ? 1 : 0);
    }

    k_out<<<BTN/256, 256, 0, stream>>>(skip, out1_w, out1_b, out2_w, out2_b, (float*)d_out);
}

// Round 4
// 2429.714 us; speedup vs baseline: 2.2716x; 2.2716x over previous
//
#include <hip/hip_runtime.h>
#include <math.h>

#define T_ 512

__device__ __forceinline__ float sigm(float x)  { return 1.0f / (1.0f + __expf(-x)); }
__device__ __forceinline__ float tanhf_(float x){ return 1.0f - 2.0f / (1.0f + __expf(2.0f * x)); }

// ---------------------------------------------------------------------------
// prep: AT[j*128+i] = A[i*128+j] ; in_wT[c*16+k] = in_w[k*96+c]
// grid = 70 blocks x 256 = 17920 = 16384 + 1536 exactly
// ---------------------------------------------------------------------------
__global__ __launch_bounds__(256) void k_prep(const float* __restrict__ A,
                                              const float* __restrict__ in_w,
                                              float* __restrict__ AT,
                                              float* __restrict__ in_wT)
{
    int idx = blockIdx.x * 256 + threadIdx.x;
    if (idx < 16384) {
        int j = idx >> 7, i = idx & 127;
        AT[idx] = A[i * 128 + j];
    } else {
        int e = idx - 16384;          // e = c*16 + k
        int c = e >> 4, k = e & 15;
        in_wT[e] = in_w[k * 96 + c];
    }
}

// ---------------------------------------------------------------------------
// Fully fused net: one block per (b,t). xres lives in LDS, skip in registers.
// Thread (i = tid&127, fh = tid>>7) owns node i, channel half [fh*16, fh*16+16).
//
// TWO coordinate systems (the reference's raw reshape is NOT a transpose):
//   conv path  : raw reshape [B,T,N,H]->[B*N,T,H]; elem (s=b*128+i, tau=t)
//                lives at flat row q0 = (b*128+i)*512 + t   (X read at q0, q0-d)
//   xres path  : true [B,T,N,H] coords; node i at (b,t) is flat row btid*128+i
// ---------------------------------------------------------------------------
__global__ __launch_bounds__(256, 4) void k_fused(
    const float* __restrict__ X,
    const float* __restrict__ AT,
    const float* __restrict__ in_wT,
    const float* __restrict__ in_b,
    const float* __restrict__ ct_w,  const float* __restrict__ ct_b,
    const float* __restrict__ cs_w,  const float* __restrict__ cs_b,
    const float* __restrict__ gcn_w, const float* __restrict__ gcn_b,
    const float* __restrict__ res_w, const float* __restrict__ res_b,
    const float* __restrict__ skip_w,const float* __restrict__ skip_b,
    const float* __restrict__ w1,    const float* __restrict__ b1,
    const float* __restrict__ w2,    const float* __restrict__ b2,
    float* __restrict__ out)
{
    __shared__ float xs[128 * 36];   // xres state tile
    __shared__ float hs[128 * 36];   // Ax / h / head exchange

    const int btid = blockIdx.x;           // b*512 + t
    const int b = btid >> 9, t = btid & (T_ - 1);
    const int tid = threadIdx.x;
    const int i = tid & 127;
    const int fh = tid >> 7;               // wave-uniform
    const int fh16 = fh * 16;

    const size_t q0 = (size_t)(b * 128 + i) * T_ + t;   // conv-coordinate X row

    // ---- conv-path current X row (kept in regs for the whole kernel) ----
    float Xc[16];
    {
        const float4* c4 = (const float4*)(X + q0 * 16);
#pragma unroll
        for (int k = 0; k < 4; ++k) {
            float4 v = c4[k];
            Xc[4*k+0] = v.x; Xc[4*k+1] = v.y; Xc[4*k+2] = v.z; Xc[4*k+3] = v.w;
        }
    }

    // ---- init xres half into LDS from TRUE-coordinate X row (coalesced) ----
    {
        float Xr[16];
        const float4* r4 = (const float4*)(X + ((size_t)btid * 128 + i) * 16);
#pragma unroll
        for (int k = 0; k < 4; ++k) {
            float4 v = r4[k];
            Xr[4*k+0] = v.x; Xr[4*k+1] = v.y; Xr[4*k+2] = v.z; Xr[4*k+3] = v.w;
        }
        float4* xrow = (float4*)(xs + i * 36 + fh16);
#pragma unroll
        for (int q = 0; q < 4; ++q) {
            float v[4];
#pragma unroll
            for (int u = 0; u < 4; ++u) {
                int c = fh16 + q * 4 + u;
                float a = in_b[64 + c];
                const float4* wr = (const float4*)(in_wT + (64 + c) * 16);
#pragma unroll
                for (int k4 = 0; k4 < 4; ++k4) {
                    float4 w = wr[k4];
                    a = fmaf(Xr[4*k4+0], w.x, a);
                    a = fmaf(Xr[4*k4+1], w.y, a);
                    a = fmaf(Xr[4*k4+2], w.z, a);
                    a = fmaf(Xr[4*k4+3], w.w, a);
                }
                v[u] = a;
            }
            xrow[q] = make_float4(v[0], v[1], v[2], v[3]);
        }
    }

    float sk[16];                    // skip accumulator (registers, all layers)
#pragma unroll
    for (int q = 0; q < 16; ++q) sk[q] = 0.f;

    __syncthreads();                 // xs tile ready

#pragma unroll 1
    for (int l = 0; l < 4; ++l) {
        const int d = 1 << l;
        const bool pv = (t >= d);    // block-uniform causal validity (tau = t)
        const float* wt  = ct_w + l * 2048;  const float* btc = ct_b + l * 32;
        const float* wsg = cs_w + l * 2048;  const float* bsc = cs_b + l * 32;
        const float* gw  = gcn_w + l * 1024; const float* gb  = gcn_b + l * 32;
        const float* rw  = res_w + l * 1024; const float* rb  = res_b + l * 32;
        const float* sw  = skip_w + l * 1024;const float* sb  = skip_b + l * 32;

        // ---- previous-tap X row (conv coords) ----
        float Xp[16];
        if (pv) {
            const float4* p4 = (const float4*)(X + (q0 - (size_t)d) * 16);
#pragma unroll
            for (int k = 0; k < 4; ++k) {
                float4 v = p4[k];
                Xp[4*k+0] = v.x; Xp[4*k+1] = v.y; Xp[4*k+2] = v.z; Xp[4*k+3] = v.w;
            }
        } else {
#pragma unroll
            for (int k = 0; k < 16; ++k) Xp[k] = 0.f;
        }

        // ---- gated causal conv, projections recomputed per ci ----
        float g[16], ac[16];
#pragma unroll
        for (int co = 0; co < 16; ++co) { g[co] = btc[fh16 + co]; ac[co] = bsc[fh16 + co]; }

#pragma unroll 4
        for (int ci = 0; ci < 32; ++ci) {
            // branch A projection (channel ci)
            float a1 = in_b[ci], a0 = in_b[ci];
            {
                const float4* wr = (const float4*)(in_wT + ci * 16);
#pragma unroll
                for (int k4 = 0; k4 < 4; ++k4) {
                    float4 w = wr[k4];
                    a1 = fmaf(Xc[4*k4+0], w.x, a1); a1 = fmaf(Xc[4*k4+1], w.y, a1);
                    a1 = fmaf(Xc[4*k4+2], w.z, a1); a1 = fmaf(Xc[4*k4+3], w.w, a1);
                    a0 = fmaf(Xp[4*k4+0], w.x, a0); a0 = fmaf(Xp[4*k4+1], w.y, a0);
                    a0 = fmaf(Xp[4*k4+2], w.z, a0); a0 = fmaf(Xp[4*k4+3], w.w, a0);
                }
            }
            a0 = pv ? a0 : 0.f;      // causal pad zeros the *projected* input
            {
                const float4* u4 = (const float4*)(wt + ci * 32 + fh16);          // tap0
                const float4* v4 = (const float4*)(wt + 1024 + ci * 32 + fh16);   // tap1
#pragma unroll
                for (int q = 0; q < 4; ++q) {
                    float4 u = u4[q], v = v4[q];
                    g[4*q+0] = fmaf(a0, u.x, fmaf(a1, v.x, g[4*q+0]));
                    g[4*q+1] = fmaf(a0, u.y, fmaf(a1, v.y, g[4*q+1]));
                    g[4*q+2] = fmaf(a0, u.z, fmaf(a1, v.z, g[4*q+2]));
                    g[4*q+3] = fmaf(a0, u.w, fmaf(a1, v.w, g[4*q+3]));
                }
            }
            // branch B projection (channel 32+ci)
            float b1v = in_b[32 + ci], b0v = in_b[32 + ci];
            {
                const float4* wr = (const float4*)(in_wT + (32 + ci) * 16);
#pragma unroll
                for (int k4 = 0; k4 < 4; ++k4) {
                    float4 w = wr[k4];
                    b1v = fmaf(Xc[4*k4+0], w.x, b1v); b1v = fmaf(Xc[4*k4+1], w.y, b1v);
                    b1v = fmaf(Xc[4*k4+2], w.z, b1v); b1v = fmaf(Xc[4*k4+3], w.w, b1v);
                    b0v = fmaf(Xp[4*k4+0], w.x, b0v); b0v = fmaf(Xp[4*k4+1], w.y, b0v);
                    b0v = fmaf(Xp[4*k4+2], w.z, b0v); b0v = fmaf(Xp[4*k4+3], w.w, b0v);
                }
            }
            b0v = pv ? b0v : 0.f;
            {
                const float4* u4 = (const float4*)(wsg + ci * 32 + fh16);
                const float4* v4 = (const float4*)(wsg + 1024 + ci * 32 + fh16);
#pragma unroll
                for (int q = 0; q < 4; ++q) {
                    float4 u = u4[q], v = v4[q];
                    ac[4*q+0] = fmaf(b0v, u.x, fmaf(b1v, v.x, ac[4*q+0]));
                    ac[4*q+1] = fmaf(b0v, u.y, fmaf(b1v, v.y, ac[4*q+1]));
                    ac[4*q+2] = fmaf(b0v, u.z, fmaf(b1v, v.z, ac[4*q+2]));
                    ac[4*q+3] = fmaf(b0v, u.w, fmaf(b1v, v.w, ac[4*q+3]));
                }
            }
        }
#pragma unroll
        for (int co = 0; co < 16; ++co)
            g[co] = tanhf_(g[co]) * sigm(ac[co]);   // g now holds tc

        // ---- A-mix: acc = sum_j A[i,j] * xs[j, fh-half] ----
        float acc[16];
#pragma unroll
        for (int q = 0; q < 16; ++q) acc[q] = 0.f;
        const float* ATp = AT + i;
#pragma unroll 2
        for (int j = 0; j < 128; ++j) {
            float a = ATp[j << 7];                         // lane-coalesced
            const float4* xr = (const float4*)(xs + j * 36 + fh16);  // wave-uniform broadcast
#pragma unroll
            for (int q = 0; q < 4; ++q) {
                float4 v = xr[q];
                acc[4*q+0] = fmaf(a, v.x, acc[4*q+0]);
                acc[4*q+1] = fmaf(a, v.y, acc[4*q+1]);
                acc[4*q+2] = fmaf(a, v.z, acc[4*q+2]);
                acc[4*q+3] = fmaf(a, v.w, acc[4*q+3]);
            }
        }
        {
            float4* hrow = (float4*)(hs + i * 36 + fh16);
#pragma unroll
            for (int q = 0; q < 4; ++q)
                hrow[q] = make_float4(acc[4*q], acc[4*q+1], acc[4*q+2], acc[4*q+3]);
        }
        __syncthreads();   // (a) Ax ready

        // ---- gcn: h = Ax_row @ gw + gb ; h += tc ----
        float h[16];
#pragma unroll
        for (int q = 0; q < 16; ++q) h[q] = gb[fh16 + q];
        {
            const float4* arow = (const float4*)(hs + i * 36);
#pragma unroll 2
            for (int f4 = 0; f4 < 8; ++f4) {
                float4 av = arow[f4];
                float avs[4] = { av.x, av.y, av.z, av.w };
#pragma unroll
                for (int u = 0; u < 4; ++u) {
                    float a = avs[u];
                    const float4* w4 = (const float4*)(gw + (f4*4+u) * 32 + fh16);
#pragma unroll
                    for (int q = 0; q < 4; ++q) {
                        float4 w = w4[q];
                        h[4*q+0] = fmaf(a, w.x, h[4*q+0]);
                        h[4*q+1] = fmaf(a, w.y, h[4*q+1]);
                        h[4*q+2] = fmaf(a, w.z, h[4*q+2]);
                        h[4*q+3] = fmaf(a, w.w, h[4*q+3]);
                    }
                }
            }
        }
#pragma unroll
        for (int q = 0; q < 16; ++q) h[q] += g[q];

        __syncthreads();   // (b) all Ax reads done
        {
            float4* hrow = (float4*)(hs + i * 36 + fh16);
#pragma unroll
            for (int q = 0; q < 4; ++q)
                hrow[q] = make_float4(h[4*q], h[4*q+1], h[4*q+2], h[4*q+3]);
        }
        __syncthreads();   // (c) h ready

        // ---- res & skip mixes from full h row ----
        float r[16];
#pragma unroll
        for (int q = 0; q < 16; ++q) { r[q] = rb[fh16 + q]; sk[q] += sb[fh16 + q]; }
        {
            const float4* hrow = (const float4*)(hs + i * 36);
#pragma unroll 2
            for (int f4 = 0; f4 < 8; ++f4) {
                float4 hv = hrow[f4];
                float hvs[4] = { hv.x, hv.y, hv.z, hv.w };
#pragma unroll
                for (int u = 0; u < 4; ++u) {
                    float a = hvs[u];
                    const float4* rw4 = (const float4*)(rw + (f4*4+u) * 32 + fh16);
                    const float4* sw4 = (const float4*)(sw + (f4*4+u) * 32 + fh16);
#pragma unroll
                    for (int q = 0; q < 4; ++q) {
                        float4 wR = rw4[q], wS = sw4[q];
                        r[4*q+0] = fmaf(a, wR.x, r[4*q+0]);
                        r[4*q+1] = fmaf(a, wR.y, r[4*q+1]);
                        r[4*q+2] = fmaf(a, wR.z, r[4*q+2]);
                        r[4*q+3] = fmaf(a, wR.w, r[4*q+3]);
                        sk[4*q+0] = fmaf(a, wS.x, sk[4*q+0]);
                        sk[4*q+1] = fmaf(a, wS.y, sk[4*q+1]);
                        sk[4*q+2] = fmaf(a, wS.z, sk[4*q+2]);
                        sk[4*q+3] = fmaf(a, wS.w, sk[4*q+3]);
                    }
                }
            }
        }
        // xres update (exclusive half-row per thread)
        {
            float* xrow = xs + i * 36 + fh16;
#pragma unroll
            for (int q = 0; q < 16; ++q) xrow[q] += r[q];
        }
        __syncthreads();   // (d) xs updated, hs reads done
    }

    // ---- output head ----
    {
        float4* srow = (float4*)(hs + i * 36 + fh16);
#pragma unroll
        for (int q = 0; q < 4; ++q)
            srow[q] = make_float4(fmaxf(sk[4*q+0], 0.f), fmaxf(sk[4*q+1], 0.f),
                                  fmaxf(sk[4*q+2], 0.f), fmaxf(sk[4*q+3], 0.f));
    }
    __syncthreads();

    float h1[16];
#pragma unroll
    for (int q = 0; q < 16; ++q) h1[q] = b1[fh16 + q];
    {
        const float4* srow = (const float4*)(hs + i * 36);
#pragma unroll 2
        for (int f4 = 0; f4 < 8; ++f4) {
            float4 sv = srow[f4];
            float svs[4] = { sv.x, sv.y, sv.z, sv.w };
#pragma unroll
            for (int u = 0; u < 4; ++u) {
                float a = svs[u];
                const float4* w4 = (const float4*)(w1 + (f4*4+u) * 32 + fh16);
#pragma unroll
                for (int q = 0; q < 4; ++q) {
                    float4 w = w4[q];
                    h1[4*q+0] = fmaf(a, w.x, h1[4*q+0]);
                    h1[4*q+1] = fmaf(a, w.y, h1[4*q+1]);
                    h1[4*q+2] = fmaf(a, w.z, h1[4*q+2]);
                    h1[4*q+3] = fmaf(a, w.w, h1[4*q+3]);
                }
            }
        }
    }
    __syncthreads();   // done reading relu(skip)
    {
        float4* hrow = (float4*)(hs + i * 36 + fh16);
#pragma unroll
        for (int q = 0; q < 4; ++q)
            hrow[q] = make_float4(fmaxf(h1[4*q+0], 0.f), fmaxf(h1[4*q+1], 0.f),
                                  fmaxf(h1[4*q+2], 0.f), fmaxf(h1[4*q+3], 0.f));
    }
    __syncthreads();

    const int fh8 = fh * 8;
    float o[8];
#pragma unroll
    for (int q = 0; q < 8; ++q) o[q] = b2[fh8 + q];
    {
        const float4* hrow = (const float4*)(hs + i * 36);
#pragma unroll 2
        for (int f4 = 0; f4 < 8; ++f4) {
            float4 hv = hrow[f4];
            float hvs[4] = { hv.x, hv.y, hv.z, hv.w };
#pragma unroll
            for (int u = 0; u < 4; ++u) {
                float a = hvs[4*0+u];
                const float4* w4 = (const float4*)(w2 + (f4*4+u) * 16 + fh8);
#pragma unroll
                for (int q = 0; q < 2; ++q) {
                    float4 w = w4[q];
                    o[4*q+0] = fmaf(a, w.x, o[4*q+0]);
                    o[4*q+1] = fmaf(a, w.y, o[4*q+1]);
                    o[4*q+2] = fmaf(a, w.z, o[4*q+2]);
                    o[4*q+3] = fmaf(a, w.w, o[4*q+3]);
                }
            }
        }
    }
    {
        float4* og = (float4*)(out + ((size_t)btid * 128 + i) * 16 + fh8);
        og[0] = make_float4(o[0], o[1], o[2], o[3]);
        og[1] = make_float4(o[4], o[5], o[6], o[7]);
    }
}

// ---------------------------------------------------------------------------
extern "C" void kernel_launch(void* const* d_in, const int* in_sizes, int n_in,
                              void* d_out, int out_size, void* d_ws, size_t ws_size,
                              hipStream_t stream)
{
    const float* X      = (const float*)d_in[0];
    const float* A      = (const float*)d_in[1];
    const float* in_w   = (const float*)d_in[2];
    const float* in_b   = (const float*)d_in[3];
    const float* ct_w   = (const float*)d_in[4];
    const float* ct_b   = (const float*)d_in[5];
    const float* cs_w   = (const float*)d_in[6];
    const float* cs_b   = (const float*)d_in[7];
    const float* gcn_w  = (const float*)d_in[8];
    const float* gcn_b  = (const float*)d_in[9];
    const float* res_w  = (const float*)d_in[10];
    const float* res_b  = (const float*)d_in[11];
    const float* skip_w = (const float*)d_in[12];
    const float* skip_b = (const float*)d_in[13];
    const float* out1_w = (const float*)d_in[14];
    const float* out1_b = (const float*)d_in[15];
    const float* out2_w = (const float*)d_in[16];
    const float* out2_b = (const float*)d_in[17];

    float* AT    = (float*)d_ws;           // 16384 floats
    float* in_wT = AT + 16384;             // 1536 floats

    k_prep<<<70, 256, 0, stream>>>(A, in_w, AT, in_wT);

    k_fused<<<8 * T_, 256, 0, stream>>>(X, AT, in_wT, in_b,
                                        ct_w, ct_b, cs_w, cs_b,
                                        gcn_w, gcn_b, res_w, res_b,
                                        skip_w, skip_b,
                                        out1_w, out1_b, out2_w, out2_b,
                                        (float*)d_out);
}